// Round 1
// baseline (1099.121 us; speedup 1.0000x reference)
//
#include <hip/hip_runtime.h>
#include <hip/hip_bf16.h>

#define CH   128
#define HH   64
#define WW   64
#define BB   8
#define OFFC 18

// ---------------------------------------------------------------------------
// Transpose deform weights (Co,Ci,3,3) -> wT[k][i][o]  (k=ky*3+kx)
// ---------------------------------------------------------------------------
__global__ __launch_bounds__(256) void transpose_w_kernel(
    const float* __restrict__ w, float* __restrict__ wT)
{
    int id = blockIdx.x * 256 + threadIdx.x;      // total 128*128*9 = 147456
    int k = id % 9;
    int rest = id / 9;
    int i = rest % CH;
    int o = rest / CH;
    wT[(k * CH + i) * CH + o] = w[id];
}

// ---------------------------------------------------------------------------
// Offset conv: 3x3, stride 1, pad 1.  x:(B,128,64,64) w:(18,128,3,3) b:(18)
// One thread per output element. id = ((b*18+co)*64+oh)*64+ow
// ---------------------------------------------------------------------------
__global__ __launch_bounds__(256) void off_conv_kernel(
    const float* __restrict__ x, const float* __restrict__ w,
    const float* __restrict__ bias, float* __restrict__ out)
{
    int id = blockIdx.x * 256 + threadIdx.x;      // total 8*18*64*64 = 589824
    int ow = id & 63;
    int oh = (id >> 6) & 63;
    int t  = id >> 12;
    int co = t % OFFC;
    int b  = t / OFFC;

    float acc = bias[co];
    const float* xb = x + (size_t)b * CH * HH * WW;
    const float* wc = w + (size_t)co * CH * 9;

    for (int ci = 0; ci < CH; ++ci) {
        const float* xi = xb + ci * HH * WW;
        const float* wi = wc + ci * 9;
        #pragma unroll
        for (int ky = 0; ky < 3; ++ky) {
            int ih = oh - 1 + ky;
            if (ih < 0 || ih >= HH) continue;
            const float* xr = xi + ih * WW;
            #pragma unroll
            for (int kx = 0; kx < 3; ++kx) {
                int iw = ow - 1 + kx;
                if (iw < 0 || iw >= WW) continue;
                acc += xr[iw] * wi[ky * 3 + kx];
            }
        }
    }
    out[id] = acc;
}

// ---------------------------------------------------------------------------
// Fused deformable conv (K=3, stride 1, pad 2, dil 2) + BN (+residual) + ReLU
// One block per (b, oh) row: 512 blocks x 256 threads.
// Per tap k: stage sampled[i=128][ow=64] in LDS, then FMA into per-thread
// acc[8 o][4 ow].  Weights read from pre-transposed wT[k][i][o].
// ---------------------------------------------------------------------------
__global__ __launch_bounds__(256) void deform_kernel(
    const float* __restrict__ x,      // (B,128,64,64) input being sampled
    const float* __restrict__ off,    // (B,18,64,64)
    const float* __restrict__ wT,     // [9][128][128] = [k][i][o]
    const float* __restrict__ g, const float* __restrict__ beta,
    const float* __restrict__ m, const float* __restrict__ v,
    const float* __restrict__ residual,   // may be nullptr
    float* __restrict__ out)
{
    __shared__ float s[CH][WW];     // 32 KB sampled values for current k
    __shared__ float cw[4][WW];     // per-corner bilinear weights (0 if invalid)
    __shared__ int   cidx[4][WW];   // per-corner clamped spatial index iy*W+ix

    int blk = blockIdx.x;
    int b  = blk >> 6;
    int oh = blk & 63;
    int tid = threadIdx.x;
    int tx = tid & 15;        // ow group
    int ty = tid >> 4;        // o group
    int ow0 = tx * 4;
    int o0  = ty * 8;

    const float* xb = x + (size_t)b * CH * HH * WW;

    float acc[8][4];
    #pragma unroll
    for (int a = 0; a < 8; ++a)
        #pragma unroll
        for (int q = 0; q < 4; ++q) acc[a][q] = 0.f;

    for (int k = 0; k < 9; ++k) {
        int ky = k / 3, kx = k % 3;

        // ---- phase A: coords for the 64 ow positions -------------------
        if (tid < WW) {
            int ow = tid;
            float dy = off[(((size_t)b * OFFC + 2 * k) * HH + oh) * WW + ow];
            float dx = off[(((size_t)b * OFFC + 2 * k + 1) * HH + oh) * WW + ow];
            float ys = (float)(oh - 2 + ky * 2) + dy;
            float xs = (float)(ow - 2 + kx * 2) + dx;
            float y0f = floorf(ys), x0f = floorf(xs);
            float fy = ys - y0f, fx = xs - x0f;
            int y0 = (int)y0f, x0 = (int)x0f;
            int y1 = y0 + 1,   x1 = x0 + 1;
            bool vy0 = (y0 >= 0) & (y0 < HH);
            bool vy1 = (y1 >= 0) & (y1 < HH);
            bool vx0 = (x0 >= 0) & (x0 < WW);
            bool vx1 = (x1 >= 0) & (x1 < WW);
            int y0c = min(max(y0, 0), HH - 1), y1c = min(max(y1, 0), HH - 1);
            int x0c = min(max(x0, 0), WW - 1), x1c = min(max(x1, 0), WW - 1);
            cw[0][ow] = (1.f - fy) * (1.f - fx) * ((vy0 && vx0) ? 1.f : 0.f);
            cw[1][ow] = (1.f - fy) * fx         * ((vy0 && vx1) ? 1.f : 0.f);
            cw[2][ow] = fy * (1.f - fx)         * ((vy1 && vx0) ? 1.f : 0.f);
            cw[3][ow] = fy * fx                 * ((vy1 && vx1) ? 1.f : 0.f);
            cidx[0][ow] = y0c * WW + x0c;
            cidx[1][ow] = y0c * WW + x1c;
            cidx[2][ow] = y1c * WW + x0c;
            cidx[3][ow] = y1c * WW + x1c;
        }
        __syncthreads();

        // ---- phase B: sample 128x64 values into LDS --------------------
        #pragma unroll 4
        for (int it = 0; it < 32; ++it) {
            int j  = tid + (it << 8);
            int i  = j >> 6;
            int ow = j & 63;
            const float* xi = xb + i * HH * WW;
            float val = cw[0][ow] * xi[cidx[0][ow]]
                      + cw[1][ow] * xi[cidx[1][ow]]
                      + cw[2][ow] * xi[cidx[2][ow]]
                      + cw[3][ow] * xi[cidx[3][ow]];
            s[i][ow] = val;
        }
        __syncthreads();

        // ---- phase C: acc[o][ow] += wT[k][i][o] * s[i][ow] -------------
        const float* wk = wT + (size_t)k * CH * CH;
        #pragma unroll 2
        for (int i = 0; i < CH; ++i) {
            float4 sv = *(const float4*)&s[i][ow0];
            const float4* wp = (const float4*)(wk + i * CH + o0);
            float4 wa = wp[0];
            float4 wb = wp[1];
            float wv[8] = {wa.x, wa.y, wa.z, wa.w, wb.x, wb.y, wb.z, wb.w};
            #pragma unroll
            for (int oo = 0; oo < 8; ++oo) {
                acc[oo][0] += wv[oo] * sv.x;
                acc[oo][1] += wv[oo] * sv.y;
                acc[oo][2] += wv[oo] * sv.z;
                acc[oo][3] += wv[oo] * sv.w;
            }
        }
        __syncthreads();
    }

    // ---- epilogue: BN (+ residual) + ReLU, float4 stores ---------------
    #pragma unroll
    for (int oo = 0; oo < 8; ++oo) {
        int o = o0 + oo;
        float inv = g[o] / sqrtf(v[o] + 1e-5f);
        float sh  = beta[o] - m[o] * inv;
        size_t base = (((size_t)b * CH + o) * HH + oh) * WW + ow0;
        float4 r;
        r.x = acc[oo][0] * inv + sh;
        r.y = acc[oo][1] * inv + sh;
        r.z = acc[oo][2] * inv + sh;
        r.w = acc[oo][3] * inv + sh;
        if (residual != nullptr) {
            float4 rs = *(const float4*)&residual[base];
            r.x += rs.x; r.y += rs.y; r.z += rs.z; r.w += rs.w;
        }
        r.x = fmaxf(r.x, 0.f); r.y = fmaxf(r.y, 0.f);
        r.z = fmaxf(r.z, 0.f); r.w = fmaxf(r.w, 0.f);
        *(float4*)&out[base] = r;
    }
}

// ---------------------------------------------------------------------------
extern "C" void kernel_launch(void* const* d_in, const int* in_sizes, int n_in,
                              void* d_out, int out_size, void* d_ws, size_t ws_size,
                              hipStream_t stream)
{
    const float* x      = (const float*)d_in[0];
    const float* w_off1 = (const float*)d_in[1];
    const float* b_off1 = (const float*)d_in[2];
    const float* w_dc1  = (const float*)d_in[3];
    const float* g1     = (const float*)d_in[4];
    const float* beta1  = (const float*)d_in[5];
    const float* m1     = (const float*)d_in[6];
    const float* v1     = (const float*)d_in[7];
    const float* w_off2 = (const float*)d_in[8];
    const float* b_off2 = (const float*)d_in[9];
    const float* w_dc2  = (const float*)d_in[10];
    const float* g2     = (const float*)d_in[11];
    const float* beta2  = (const float*)d_in[12];
    const float* m2     = (const float*)d_in[13];
    const float* v2     = (const float*)d_in[14];
    float* out = (float*)d_out;

    char* ws = (char*)d_ws;
    float* out1 = (float*)ws;                                   // 16,777,216 B
    float* offb = (float*)(ws + 16777216);                      //  2,359,296 B
    float* wT1  = (float*)(ws + 16777216 + 2359296);            //    589,824 B
    float* wT2  = wT1 + 147456;                                 //    589,824 B

    // Pre-transpose both deform weight tensors.
    transpose_w_kernel<<<576, 256, 0, stream>>>(w_dc1, wT1);
    transpose_w_kernel<<<576, 256, 0, stream>>>(w_dc2, wT2);

    // Layer 1
    off_conv_kernel<<<2304, 256, 0, stream>>>(x, w_off1, b_off1, offb);
    deform_kernel<<<512, 256, 0, stream>>>(x, offb, wT1, g1, beta1, m1, v1,
                                           nullptr, out1);
    // Layer 2
    off_conv_kernel<<<2304, 256, 0, stream>>>(out1, w_off2, b_off2, offb);
    deform_kernel<<<512, 256, 0, stream>>>(out1, offb, wT2, g2, beta2, m2, v2,
                                           x, out);
}

// Round 2
// 846.020 us; speedup vs baseline: 1.2992x; 1.2992x over previous
//
#include <hip/hip_runtime.h>
#include <hip/hip_bf16.h>

#define CH   128
#define HH   64
#define WW   64
#define BB   8
#define OFFC 18

// ---------------------------------------------------------------------------
// Transpose deform weights (Co,Ci,3,3) -> wT[k][i][o]  (k=ky*3+kx)
// ---------------------------------------------------------------------------
__global__ __launch_bounds__(256) void transpose_w_kernel(
    const float* __restrict__ w, float* __restrict__ wT)
{
    int id = blockIdx.x * 256 + threadIdx.x;      // total 128*128*9 = 147456
    int k = id % 9;
    int rest = id / 9;
    int i = rest % CH;
    int o = rest / CH;
    wT[(k * CH + i) * CH + o] = w[id];
}

// ---------------------------------------------------------------------------
// Offset conv v2: 3x3, stride 1, pad 1.  x:(B,128,64,64) w:(18,128,3,3)
// Block = (b, co, oh-tile of 16). 256 threads: tx=tid&15 -> ow0=4*tx,
// ohi=tid>>4 -> oh. Weights for this co staged in LDS padded [128][12]
// (16B-aligned -> 2x ds_read_b128 per ci, wave-uniform broadcast).
// Each thread: 4 ow outputs, 36 FMA/ci, float4 row loads from global.
// ---------------------------------------------------------------------------
__global__ __launch_bounds__(256) void off_conv_kernel(
    const float* __restrict__ x, const float* __restrict__ w,
    const float* __restrict__ bias, float* __restrict__ out)
{
    __shared__ float w_lds[CH * 12];   // 6 KB, padded 9->12 per ci

    int blk = blockIdx.x;              // ((b*18 + co)*4 + oht)
    int oht = blk & 3;
    int t   = blk >> 2;
    int co  = t % OFFC;
    int b   = t / OFFC;

    int tid = threadIdx.x;
    int tx  = tid & 15;
    int ohi = tid >> 4;
    int ow0 = tx * 4;
    int oh  = oht * 16 + ohi;

    // stage weights for this co: w[co][ci][tap] -> w_lds[ci*12 + tap]
    const float* wc = w + (size_t)co * CH * 9;
    for (int j = tid; j < CH * 9; j += 256)
        w_lds[(j / 9) * 12 + (j % 9)] = wc[j];
    __syncthreads();

    float bco = bias[co];
    float acc0 = bco, acc1 = bco, acc2 = bco, acc3 = bco;

    const float* xb = x + (size_t)b * CH * HH * WW;

    for (int ci = 0; ci < CH; ++ci) {
        const float4* wl = (const float4*)&w_lds[ci * 12];
        float4 wA = wl[0];                 // taps 0..3
        float4 wB = wl[1];                 // taps 4..7
        float  w8 = w_lds[ci * 12 + 8];    // tap 8
        const float* xci = xb + (size_t)ci * HH * WW;

        #pragma unroll
        for (int ky = 0; ky < 3; ++ky) {
            int ih = oh - 1 + ky;
            if (ih < 0 || ih >= HH) continue;
            const float* xr = xci + ih * WW;
            float4 c = *(const float4*)&xr[ow0];
            float lft = (ow0 > 0)      ? xr[ow0 - 1] : 0.f;
            float rgt = (ow0 + 4 < WW) ? xr[ow0 + 4] : 0.f;
            float t0, t1, t2;
            if      (ky == 0) { t0 = wA.x; t1 = wA.y; t2 = wA.z; }
            else if (ky == 1) { t0 = wA.w; t1 = wB.x; t2 = wB.y; }
            else              { t0 = wB.z; t1 = wB.w; t2 = w8;   }
            acc0 += t0 * lft + t1 * c.x + t2 * c.y;
            acc1 += t0 * c.x + t1 * c.y + t2 * c.z;
            acc2 += t0 * c.y + t1 * c.z + t2 * c.w;
            acc3 += t0 * c.z + t1 * c.w + t2 * rgt;
        }
    }

    size_t obase = (((size_t)b * OFFC + co) * HH + oh) * WW + ow0;
    float4 r; r.x = acc0; r.y = acc1; r.z = acc2; r.w = acc3;
    *(float4*)&out[obase] = r;
}

// ---------------------------------------------------------------------------
// Fused deformable conv (K=3, stride 1, pad 2, dil 2) + BN (+residual) + ReLU
// One block per (b, oh) row: 512 blocks x 256 threads.
// ---------------------------------------------------------------------------
__global__ __launch_bounds__(256) void deform_kernel(
    const float* __restrict__ x,      // (B,128,64,64) input being sampled
    const float* __restrict__ off,    // (B,18,64,64)
    const float* __restrict__ wT,     // [9][128][128] = [k][i][o]
    const float* __restrict__ g, const float* __restrict__ beta,
    const float* __restrict__ m, const float* __restrict__ v,
    const float* __restrict__ residual,   // may be nullptr
    float* __restrict__ out)
{
    __shared__ float s[CH][WW];     // 32 KB sampled values for current k
    __shared__ float cw[4][WW];     // per-corner bilinear weights (0 if invalid)
    __shared__ int   cidx[4][WW];   // per-corner clamped spatial index iy*W+ix

    int blk = blockIdx.x;
    int b  = blk >> 6;
    int oh = blk & 63;
    int tid = threadIdx.x;
    int tx = tid & 15;        // ow group
    int ty = tid >> 4;        // o group
    int ow0 = tx * 4;
    int o0  = ty * 8;

    const float* xb = x + (size_t)b * CH * HH * WW;

    float acc[8][4];
    #pragma unroll
    for (int a = 0; a < 8; ++a)
        #pragma unroll
        for (int q = 0; q < 4; ++q) acc[a][q] = 0.f;

    for (int k = 0; k < 9; ++k) {
        int ky = k / 3, kx = k % 3;

        // ---- phase A: coords for the 64 ow positions -------------------
        if (tid < WW) {
            int ow = tid;
            float dy = off[(((size_t)b * OFFC + 2 * k) * HH + oh) * WW + ow];
            float dx = off[(((size_t)b * OFFC + 2 * k + 1) * HH + oh) * WW + ow];
            float ys = (float)(oh - 2 + ky * 2) + dy;
            float xs = (float)(ow - 2 + kx * 2) + dx;
            float y0f = floorf(ys), x0f = floorf(xs);
            float fy = ys - y0f, fx = xs - x0f;
            int y0 = (int)y0f, x0 = (int)x0f;
            int y1 = y0 + 1,   x1 = x0 + 1;
            bool vy0 = (y0 >= 0) & (y0 < HH);
            bool vy1 = (y1 >= 0) & (y1 < HH);
            bool vx0 = (x0 >= 0) & (x0 < WW);
            bool vx1 = (x1 >= 0) & (x1 < WW);
            int y0c = min(max(y0, 0), HH - 1), y1c = min(max(y1, 0), HH - 1);
            int x0c = min(max(x0, 0), WW - 1), x1c = min(max(x1, 0), WW - 1);
            cw[0][ow] = (1.f - fy) * (1.f - fx) * ((vy0 && vx0) ? 1.f : 0.f);
            cw[1][ow] = (1.f - fy) * fx         * ((vy0 && vx1) ? 1.f : 0.f);
            cw[2][ow] = fy * (1.f - fx)         * ((vy1 && vx0) ? 1.f : 0.f);
            cw[3][ow] = fy * fx                 * ((vy1 && vx1) ? 1.f : 0.f);
            cidx[0][ow] = y0c * WW + x0c;
            cidx[1][ow] = y0c * WW + x1c;
            cidx[2][ow] = y1c * WW + x0c;
            cidx[3][ow] = y1c * WW + x1c;
        }
        __syncthreads();

        // ---- phase B: sample 128x64 values into LDS --------------------
        #pragma unroll 4
        for (int it = 0; it < 32; ++it) {
            int j  = tid + (it << 8);
            int i  = j >> 6;
            int ow = j & 63;
            const float* xi = xb + i * HH * WW;
            float val = cw[0][ow] * xi[cidx[0][ow]]
                      + cw[1][ow] * xi[cidx[1][ow]]
                      + cw[2][ow] * xi[cidx[2][ow]]
                      + cw[3][ow] * xi[cidx[3][ow]];
            s[i][ow] = val;
        }
        __syncthreads();

        // ---- phase C: acc[o][ow] += wT[k][i][o] * s[i][ow] -------------
        const float* wk = wT + (size_t)k * CH * CH;
        #pragma unroll 2
        for (int i = 0; i < CH; ++i) {
            float4 sv = *(const float4*)&s[i][ow0];
            const float4* wp = (const float4*)(wk + i * CH + o0);
            float4 wa = wp[0];
            float4 wb = wp[1];
            float wv[8] = {wa.x, wa.y, wa.z, wa.w, wb.x, wb.y, wb.z, wb.w};
            #pragma unroll
            for (int oo = 0; oo < 8; ++oo) {
                acc[oo][0] += wv[oo] * sv.x;
                acc[oo][1] += wv[oo] * sv.y;
                acc[oo][2] += wv[oo] * sv.z;
                acc[oo][3] += wv[oo] * sv.w;
            }
        }
        __syncthreads();
    }

    // ---- epilogue: BN (+ residual) + ReLU, float4 stores ---------------
    #pragma unroll
    for (int oo = 0; oo < 8; ++oo) {
        int o = o0 + oo;
        float inv = g[o] / sqrtf(v[o] + 1e-5f);
        float sh  = beta[o] - m[o] * inv;
        size_t base = (((size_t)b * CH + o) * HH + oh) * WW + ow0;
        float4 r;
        r.x = acc[oo][0] * inv + sh;
        r.y = acc[oo][1] * inv + sh;
        r.z = acc[oo][2] * inv + sh;
        r.w = acc[oo][3] * inv + sh;
        if (residual != nullptr) {
            float4 rs = *(const float4*)&residual[base];
            r.x += rs.x; r.y += rs.y; r.z += rs.z; r.w += rs.w;
        }
        r.x = fmaxf(r.x, 0.f); r.y = fmaxf(r.y, 0.f);
        r.z = fmaxf(r.z, 0.f); r.w = fmaxf(r.w, 0.f);
        *(float4*)&out[base] = r;
    }
}

// ---------------------------------------------------------------------------
extern "C" void kernel_launch(void* const* d_in, const int* in_sizes, int n_in,
                              void* d_out, int out_size, void* d_ws, size_t ws_size,
                              hipStream_t stream)
{
    const float* x      = (const float*)d_in[0];
    const float* w_off1 = (const float*)d_in[1];
    const float* b_off1 = (const float*)d_in[2];
    const float* w_dc1  = (const float*)d_in[3];
    const float* g1     = (const float*)d_in[4];
    const float* beta1  = (const float*)d_in[5];
    const float* m1     = (const float*)d_in[6];
    const float* v1     = (const float*)d_in[7];
    const float* w_off2 = (const float*)d_in[8];
    const float* b_off2 = (const float*)d_in[9];
    const float* w_dc2  = (const float*)d_in[10];
    const float* g2     = (const float*)d_in[11];
    const float* beta2  = (const float*)d_in[12];
    const float* m2     = (const float*)d_in[13];
    const float* v2     = (const float*)d_in[14];
    float* out = (float*)d_out;

    char* ws = (char*)d_ws;
    float* out1 = (float*)ws;                                   // 16,777,216 B
    float* offb = (float*)(ws + 16777216);                      //  2,359,296 B
    float* wT1  = (float*)(ws + 16777216 + 2359296);            //    589,824 B
    float* wT2  = wT1 + 147456;                                 //    589,824 B

    // Pre-transpose both deform weight tensors.
    transpose_w_kernel<<<576, 256, 0, stream>>>(w_dc1, wT1);
    transpose_w_kernel<<<576, 256, 0, stream>>>(w_dc2, wT2);

    // Layer 1
    off_conv_kernel<<<576, 256, 0, stream>>>(x, w_off1, b_off1, offb);
    deform_kernel<<<512, 256, 0, stream>>>(x, offb, wT1, g1, beta1, m1, v1,
                                           nullptr, out1);
    // Layer 2
    off_conv_kernel<<<576, 256, 0, stream>>>(out1, w_off2, b_off2, offb);
    deform_kernel<<<512, 256, 0, stream>>>(out1, offb, wT2, g2, beta2, m2, v2,
                                           x, out);
}

// Round 3
// 531.433 us; speedup vs baseline: 2.0682x; 1.5920x over previous
//
#include <hip/hip_runtime.h>
#include <hip/hip_bf16.h>

#define CH   128
#define HH   64
#define WW   64
#define OFFC 18

typedef __attribute__((ext_vector_type(8))) short bf16x8;
typedef __attribute__((ext_vector_type(4))) float f32x4;

static __device__ __forceinline__ unsigned short f2bf(float f) {
    __hip_bfloat16 h = __float2bfloat16(f);
    return *reinterpret_cast<unsigned short*>(&h);
}

// ---------------------------------------------------------------------------
// Pack deform weights (Co,Ci,3,3) f32 -> bf16 A-fragment order for
// mfma_f32_16x16x32_bf16:  wpk[((k*4+kk)*8 + ot)*512 + lane*8 + j]
//   = w[o][i][k],  o = ot*16 + (lane&15),  i = kk*32 + (lane>>4)*8 + j
// ---------------------------------------------------------------------------
__global__ __launch_bounds__(256) void pack_w_kernel(
    const float* __restrict__ w, unsigned short* __restrict__ wpk)
{
    int id = blockIdx.x * 256 + threadIdx.x;     // 147456 total
    int j    = id & 7;
    int lane = (id >> 3) & 63;
    int ot   = (id >> 9) & 7;
    int kk   = (id >> 12) & 3;
    int k    = id >> 14;                         // 0..8
    int o = ot * 16 + (lane & 15);
    int i = kk * 32 + (lane >> 4) * 8 + j;
    wpk[id] = f2bf(w[(o * CH + i) * 9 + k]);
}

// ---------------------------------------------------------------------------
// Offset conv: 3x3, stride 1, pad 1 (unchanged from round 2).
// ---------------------------------------------------------------------------
__global__ __launch_bounds__(256) void off_conv_kernel(
    const float* __restrict__ x, const float* __restrict__ w,
    const float* __restrict__ bias, float* __restrict__ out)
{
    __shared__ float w_lds[CH * 12];   // 6 KB, padded 9->12 per ci

    int blk = blockIdx.x;              // ((b*18 + co)*4 + oht)
    int oht = blk & 3;
    int t   = blk >> 2;
    int co  = t % OFFC;
    int b   = t / OFFC;

    int tid = threadIdx.x;
    int tx  = tid & 15;
    int ohi = tid >> 4;
    int ow0 = tx * 4;
    int oh  = oht * 16 + ohi;

    const float* wc = w + (size_t)co * CH * 9;
    for (int j = tid; j < CH * 9; j += 256)
        w_lds[(j / 9) * 12 + (j % 9)] = wc[j];
    __syncthreads();

    float bco = bias[co];
    float acc0 = bco, acc1 = bco, acc2 = bco, acc3 = bco;

    const float* xb = x + (size_t)b * CH * HH * WW;

    for (int ci = 0; ci < CH; ++ci) {
        const float4* wl = (const float4*)&w_lds[ci * 12];
        float4 wA = wl[0];
        float4 wB = wl[1];
        float  w8 = w_lds[ci * 12 + 8];
        const float* xci = xb + (size_t)ci * HH * WW;

        #pragma unroll
        for (int ky = 0; ky < 3; ++ky) {
            int ih = oh - 1 + ky;
            if (ih < 0 || ih >= HH) continue;
            const float* xr = xci + ih * WW;
            float4 c = *(const float4*)&xr[ow0];
            float lft = (ow0 > 0)      ? xr[ow0 - 1] : 0.f;
            float rgt = (ow0 + 4 < WW) ? xr[ow0 + 4] : 0.f;
            float t0, t1, t2;
            if      (ky == 0) { t0 = wA.x; t1 = wA.y; t2 = wA.z; }
            else if (ky == 1) { t0 = wA.w; t1 = wB.x; t2 = wB.y; }
            else              { t0 = wB.z; t1 = wB.w; t2 = w8;   }
            acc0 += t0 * lft + t1 * c.x + t2 * c.y;
            acc1 += t0 * c.x + t1 * c.y + t2 * c.z;
            acc2 += t0 * c.y + t1 * c.z + t2 * c.w;
            acc3 += t0 * c.z + t1 * c.w + t2 * rgt;
        }
    }

    size_t obase = (((size_t)b * OFFC + co) * HH + oh) * WW + ow0;
    float4 r; r.x = acc0; r.y = acc1; r.z = acc2; r.w = acc3;
    *(float4*)&out[obase] = r;
}

// ---------------------------------------------------------------------------
// Deformable conv (K=3, stride 1, pad 2, dil 2) via bf16 MFMA
//   + BN (+residual) + ReLU.
// Grid 1024: blk = ((b*64 + oh)*2 + owh), XCD-swizzled so each XCD owns one b
// (2 MB image fits its 4 MB L2). 256 threads = 4 waves; wave w owns
// o in [32w, 32w+32). Per tap k: all threads sample 128i x 32ow bilinear
// values -> bf16 LDS sB[ow][i] (XOR-swizzled), then 16 mfma/wave.
// ---------------------------------------------------------------------------
__global__ __launch_bounds__(256) void deform_mfma_kernel(
    const float* __restrict__ x,      // (B,128,64,64) input being sampled
    const float* __restrict__ off,    // (B,18,64,64)
    const unsigned short* __restrict__ wpk,   // packed bf16 A-frags
    const float* __restrict__ g, const float* __restrict__ beta,
    const float* __restrict__ m, const float* __restrict__ v,
    const float* __restrict__ residual,       // may be nullptr
    float* __restrict__ out)
{
    __shared__ unsigned short sB[32 * 128];   // 8 KB bf16 [ow][i], swizzled

    // XCD-aware bijective swizzle (nwg=1024, %8==0): XCD n gets b=n entirely.
    int wgid = blockIdx.x;
    int blk  = (wgid & 7) * 128 + (wgid >> 3);
    int owh = blk & 1;
    int oh  = (blk >> 1) & 63;
    int b   = blk >> 7;
    int ow0 = owh * 32;

    int tid  = threadIdx.x;
    int lane = tid & 63;
    int wv   = tid >> 6;          // wave id 0..3

    int s_ow = tid & 31;          // sampling: local ow
    int s_ig = tid >> 5;          // sampling: i-group 0..7 (16 i each)
    int ow_g = ow0 + s_ow;

    const float* xb = x + (size_t)b * CH * HH * WW;

    f32x4 acc[2][2];              // [o-tile local][ow-tile]
    #pragma unroll
    for (int a = 0; a < 2; ++a)
        #pragma unroll
        for (int q = 0; q < 2; ++q) acc[a][q] = (f32x4){0.f, 0.f, 0.f, 0.f};

    for (int k = 0; k < 9; ++k) {
        int ky = k / 3, kx = k - ky * 3;

        // ---- per-thread bilinear coords for (oh, ow_g, tap k) ----------
        float dy = off[(((size_t)b * OFFC + 2 * k) * HH + oh) * WW + ow_g];
        float dx = off[(((size_t)b * OFFC + 2 * k + 1) * HH + oh) * WW + ow_g];
        float ys = (float)(oh - 2 + ky * 2) + dy;
        float xs = (float)(ow_g - 2 + kx * 2) + dx;
        float y0f = floorf(ys), x0f = floorf(xs);
        float fy = ys - y0f, fx = xs - x0f;
        int y0 = (int)y0f, x0 = (int)x0f;
        int y1 = y0 + 1,   x1 = x0 + 1;
        bool vy0 = (y0 >= 0) & (y0 < HH);
        bool vy1 = (y1 >= 0) & (y1 < HH);
        bool vx0 = (x0 >= 0) & (x0 < WW);
        bool vx1 = (x1 >= 0) & (x1 < WW);
        int y0c = min(max(y0, 0), HH - 1), y1c = min(max(y1, 0), HH - 1);
        int x0c = min(max(x0, 0), WW - 1), x1c = min(max(x1, 0), WW - 1);
        float cw0 = (1.f - fy) * (1.f - fx) * ((vy0 && vx0) ? 1.f : 0.f);
        float cw1 = (1.f - fy) * fx         * ((vy0 && vx1) ? 1.f : 0.f);
        float cw2 = fy * (1.f - fx)         * ((vy1 && vx0) ? 1.f : 0.f);
        float cw3 = fy * fx                 * ((vy1 && vx1) ? 1.f : 0.f);
        int ci0 = y0c * WW + x0c, ci1 = y0c * WW + x1c;
        int ci2 = y1c * WW + x0c, ci3 = y1c * WW + x1c;

        // ---- sample 16 i's, pack bf16, 2x ds_write_b128 (swizzled) -----
        #pragma unroll
        for (int c = 0; c < 2; ++c) {
            int ibase = s_ig * 16 + c * 8;
            const float* xi = xb + (size_t)ibase * HH * WW;
            union { bf16x8 v8; unsigned short u[8]; } pk;
            #pragma unroll
            for (int j = 0; j < 8; ++j) {
                const float* xp = xi + (size_t)j * HH * WW;
                float val = cw0 * xp[ci0] + cw1 * xp[ci1]
                          + cw2 * xp[ci2] + cw3 * xp[ci3];
                pk.u[j] = f2bf(val);
            }
            int byte = s_ow * 256 + ibase * 2;
            byte ^= (s_ow & 7) << 4;
            *reinterpret_cast<bf16x8*>(reinterpret_cast<char*>(sB) + byte) = pk.v8;
        }
        __syncthreads();

        // ---- MFMA: 4 K-chunks of 32 i ----------------------------------
        const unsigned short* wk = wpk + (size_t)k * 16384;
        #pragma unroll
        for (int kk = 0; kk < 4; ++kk) {
            bf16x8 a0 = *(const bf16x8*)(wk + (kk * 8 + 2 * wv)     * 512 + lane * 8);
            bf16x8 a1 = *(const bf16x8*)(wk + (kk * 8 + 2 * wv + 1) * 512 + lane * 8);
            #pragma unroll
            for (int owt = 0; owt < 2; ++owt) {
                int owl = owt * 16 + (lane & 15);
                int ib  = kk * 32 + (lane >> 4) * 8;
                int byte = owl * 256 + ib * 2;
                byte ^= (owl & 7) << 4;
                bf16x8 bf = *reinterpret_cast<const bf16x8*>(
                                reinterpret_cast<const char*>(sB) + byte);
                acc[0][owt] = __builtin_amdgcn_mfma_f32_16x16x32_bf16(
                                  a0, bf, acc[0][owt], 0, 0, 0);
                acc[1][owt] = __builtin_amdgcn_mfma_f32_16x16x32_bf16(
                                  a1, bf, acc[1][owt], 0, 0, 0);
            }
        }
        __syncthreads();
    }

    // ---- epilogue: BN (+ residual) + ReLU ------------------------------
    #pragma unroll
    for (int otl = 0; otl < 2; ++otl) {
        #pragma unroll
        for (int r = 0; r < 4; ++r) {
            int o = (2 * wv + otl) * 16 + (lane >> 4) * 4 + r;
            float inv = g[o] / sqrtf(v[o] + 1e-5f);
            float sh  = beta[o] - m[o] * inv;
            #pragma unroll
            for (int owt = 0; owt < 2; ++owt) {
                int ow = ow0 + owt * 16 + (lane & 15);
                size_t idx = (((size_t)b * CH + o) * HH + oh) * WW + ow;
                float val = acc[otl][owt][r] * inv + sh;
                if (residual != nullptr) val += residual[idx];
                out[idx] = fmaxf(val, 0.f);
            }
        }
    }
}

// ---------------------------------------------------------------------------
extern "C" void kernel_launch(void* const* d_in, const int* in_sizes, int n_in,
                              void* d_out, int out_size, void* d_ws, size_t ws_size,
                              hipStream_t stream)
{
    const float* x      = (const float*)d_in[0];
    const float* w_off1 = (const float*)d_in[1];
    const float* b_off1 = (const float*)d_in[2];
    const float* w_dc1  = (const float*)d_in[3];
    const float* g1     = (const float*)d_in[4];
    const float* beta1  = (const float*)d_in[5];
    const float* m1     = (const float*)d_in[6];
    const float* v1     = (const float*)d_in[7];
    const float* w_off2 = (const float*)d_in[8];
    const float* b_off2 = (const float*)d_in[9];
    const float* w_dc2  = (const float*)d_in[10];
    const float* g2     = (const float*)d_in[11];
    const float* beta2  = (const float*)d_in[12];
    const float* m2     = (const float*)d_in[13];
    const float* v2     = (const float*)d_in[14];
    float* out = (float*)d_out;

    char* ws = (char*)d_ws;
    float* out1 = (float*)ws;                                     // 16,777,216 B
    float* offb = (float*)(ws + 16777216);                        //  2,359,296 B
    unsigned short* wpk1 = (unsigned short*)(ws + 19136512);      //    294,912 B
    unsigned short* wpk2 = wpk1 + 147456;                         //    294,912 B

    // Pack both deform weight tensors into bf16 MFMA A-fragment order.
    pack_w_kernel<<<576, 256, 0, stream>>>(w_dc1, wpk1);
    pack_w_kernel<<<576, 256, 0, stream>>>(w_dc2, wpk2);

    // Layer 1
    off_conv_kernel<<<576, 256, 0, stream>>>(x, w_off1, b_off1, offb);
    deform_mfma_kernel<<<1024, 256, 0, stream>>>(x, offb, wpk1,
                                                 g1, beta1, m1, v1,
                                                 nullptr, out1);
    // Layer 2
    off_conv_kernel<<<576, 256, 0, stream>>>(out1, w_off2, b_off2, offb);
    deform_mfma_kernel<<<1024, 256, 0, stream>>>(out1, offb, wpk2,
                                                 g2, beta2, m2, v2,
                                                 x, out);
}

// Round 4
// 101.477 us; speedup vs baseline: 10.8312x; 5.2370x over previous
//
#include <hip/hip_runtime.h>
#include <hip/hip_bf16.h>

#define CH   128
#define HH   64
#define WW   64
#define OFFC 18

typedef __attribute__((ext_vector_type(8))) short bf16x8;
typedef __attribute__((ext_vector_type(4))) short bf16x4;
typedef __attribute__((ext_vector_type(4))) float f32x4;

static __device__ __forceinline__ unsigned short f2bf(float f) {
    __hip_bfloat16 h = __float2bfloat16(f);
    return *reinterpret_cast<unsigned short*>(&h);
}
static __device__ __forceinline__ float bf2f(unsigned short u) {
    union { unsigned int i; float f; } x; x.i = ((unsigned int)u) << 16;
    return x.f;
}

// ---------------------------------------------------------------------------
// Pack all four weight tensors to bf16 MFMA A-fragment order in one launch.
// blocks 0..575   : wdc1 -> wpk1   [((k*4+kk)*8+ot)*512 + lane*8 + j]
// blocks 576..1151: wdc2 -> wpk2
// blocks 1152..1295: wof1 -> wpo1  [((k*4+kk)*2+mt)*512 + lane*8 + j], co pad 32
// blocks 1296..1439: wof2 -> wpo2
// ---------------------------------------------------------------------------
__global__ __launch_bounds__(256) void pack_all_kernel(
    const float* __restrict__ wdc1, const float* __restrict__ wdc2,
    const float* __restrict__ wof1, const float* __restrict__ wof2,
    unsigned short* __restrict__ wpk1, unsigned short* __restrict__ wpk2,
    unsigned short* __restrict__ wpo1, unsigned short* __restrict__ wpo2)
{
    int blk = blockIdx.x;
    int tid = threadIdx.x;
    if (blk < 1152) {
        const float* w = (blk < 576) ? wdc1 : wdc2;
        unsigned short* wp = (blk < 576) ? wpk1 : wpk2;
        int id = (blk % 576) * 256 + tid;          // 0..147455
        int j    = id & 7;
        int lane = (id >> 3) & 63;
        int ot   = (id >> 9) & 7;
        int kk   = (id >> 12) & 3;
        int k    = id >> 14;
        int o = ot * 16 + (lane & 15);
        int i = kk * 32 + (lane >> 4) * 8 + j;
        wp[id] = f2bf(w[(o * CH + i) * 9 + k]);
    } else {
        const float* w = (blk < 1296) ? wof1 : wof2;
        unsigned short* wp = (blk < 1296) ? wpo1 : wpo2;
        int id = ((blk - 1152) % 144) * 256 + tid; // 0..36863
        int j    = id & 7;
        int lane = (id >> 3) & 63;
        int mt   = (id >> 9) & 1;
        int kk   = (id >> 10) & 3;
        int k    = id >> 12;
        int o = mt * 16 + (lane & 15);
        int i = kk * 32 + (lane >> 4) * 8 + j;
        wp[id] = (o < OFFC) ? f2bf(w[(o * CH + i) * 9 + k]) : (unsigned short)0;
    }
}

// ---------------------------------------------------------------------------
// x (B,C,H,W) f32  ->  xh (B,H,W,C) bf16.   One block per (b,h) row.
// ---------------------------------------------------------------------------
__global__ __launch_bounds__(256) void to_nhwc_kernel(
    const float* __restrict__ x, unsigned short* __restrict__ xh)
{
    __shared__ float s[CH][WW + 1];
    int blk = blockIdx.x;                    // b*64 + h
    int tid = threadIdx.x;
    const float* xb = x + ((size_t)(blk >> 6) * CH * HH + (blk & 63)) * WW;

    int c_off = tid >> 4, w0 = (tid & 15) * 4;
    #pragma unroll
    for (int it = 0; it < 8; ++it) {
        int c = it * 16 + c_off;
        float4 vv = *(const float4*)&xb[(size_t)c * HH * WW + w0];
        s[c][w0] = vv.x; s[c][w0 + 1] = vv.y; s[c][w0 + 2] = vv.z; s[c][w0 + 3] = vv.w;
    }
    __syncthreads();

    int w = tid & 63, c0 = (tid >> 6) * 32;
    unsigned short* dst = xh + ((size_t)blk * WW + w) * CH + c0;
    unsigned short tmp[32];
    #pragma unroll
    for (int j = 0; j < 32; ++j) tmp[j] = f2bf(s[c0 + j][w]);
    #pragma unroll
    for (int q = 0; q < 4; ++q)
        *(bf16x8*)(dst + q * 8) = *(const bf16x8*)(tmp + q * 8);
}

// ---------------------------------------------------------------------------
// Offset conv via MFMA implicit GEMM.  3x3 s1 p1, Ci=128, Co=18 (pad 32).
// Block = (b, oh) [XCD-swizzled]; 4 waves, wave nt owns ow tile [16nt,16nt+16).
// B-fragments read straight from global xh (K=ci contiguous). Out: bf16 NCHW.
// ---------------------------------------------------------------------------
__global__ __launch_bounds__(256) void off_conv_mfma_kernel(
    const unsigned short* __restrict__ xh,   // (B,64,64,128) bf16
    const unsigned short* __restrict__ wpo,  // packed A frags
    const float* __restrict__ bias,          // (18)
    unsigned short* __restrict__ offh)       // (B,18,64,64) bf16
{
    int wgid = blockIdx.x;                   // 512
    int blk  = (wgid & 7) * 64 + (wgid >> 3);
    int b = blk >> 6, oh = blk & 63;
    int tid = threadIdx.x;
    int lane = tid & 63;
    int nt = tid >> 6;
    int nl = lane & 15;
    int kg = lane >> 4;

    f32x4 acc0 = {0.f, 0.f, 0.f, 0.f}, acc1 = {0.f, 0.f, 0.f, 0.f};
    const unsigned short* xb = xh + (size_t)b * HH * WW * CH;

    for (int k = 0; k < 9; ++k) {
        int ky = k / 3, kx = k - ky * 3;
        int ih = oh - 1 + ky;
        if (ih < 0 || ih >= HH) continue;
        int iw = nt * 16 + nl + kx - 1;
        bool valid = (iw >= 0) && (iw < WW);
        const unsigned short* row = xb + ((size_t)ih * WW + (valid ? iw : 0)) * CH + kg * 8;
        const unsigned short* wk = wpo + (size_t)k * 8 * 512;
        #pragma unroll
        for (int kk = 0; kk < 4; ++kk) {
            bf16x8 bfrag = {0, 0, 0, 0, 0, 0, 0, 0};
            if (valid) bfrag = *(const bf16x8*)(row + kk * 32);
            bf16x8 a0 = *(const bf16x8*)(wk + (kk * 2 + 0) * 512 + lane * 8);
            bf16x8 a1 = *(const bf16x8*)(wk + (kk * 2 + 1) * 512 + lane * 8);
            acc0 = __builtin_amdgcn_mfma_f32_16x16x32_bf16(a0, bfrag, acc0, 0, 0, 0);
            acc1 = __builtin_amdgcn_mfma_f32_16x16x32_bf16(a1, bfrag, acc1, 0, 0, 0);
        }
    }

    int ow = nt * 16 + nl;
    #pragma unroll
    for (int r = 0; r < 4; ++r) {
        int co = kg * 4 + r;                 // M-tile 0: co 0..15
        offh[(((size_t)b * OFFC + co) * HH + oh) * WW + ow] = f2bf(acc0[r] + bias[co]);
    }
    if (kg == 0) {
        #pragma unroll
        for (int r = 0; r < 2; ++r) {
            int co = 16 + r;                 // M-tile 1: co 16,17
            offh[(((size_t)b * OFFC + co) * HH + oh) * WW + ow] = f2bf(acc1[r] + bias[co]);
        }
    }
}

// ---------------------------------------------------------------------------
// Deformable conv (K=3, s1, pad 2, dil 2) via bf16 MFMA, NHWC sampled input.
// Block = (b, oh, ow-half) [XCD-swizzled by b]; 256 thr = 4 waves.
// Sampling: thread = (ow 0..31, ci-group of 16): 4 corner rows x 2 bf16x8
// cooperative loads, f32 blend, swizzled bf16 LDS write.  MFMA: wave wv owns
// o tiles {2wv,2wv+1}; 16 mfma per tap.  Epilogue: layer1 -> NHWC bf16 (+BN,
// ReLU); layer2 -> NCHW f32 (+BN, residual, ReLU).
// ---------------------------------------------------------------------------
__global__ __launch_bounds__(256) void deform_mfma2_kernel(
    const unsigned short* __restrict__ xh,    // (B,64,64,128) bf16 (sampled)
    const unsigned short* __restrict__ offh,  // (B,18,64,64) bf16
    const unsigned short* __restrict__ wpk,   // packed A frags
    const float* __restrict__ g, const float* __restrict__ beta,
    const float* __restrict__ m, const float* __restrict__ v,
    const float* __restrict__ residual,       // layer2 only
    unsigned short* __restrict__ out_h,       // layer1: NHWC bf16 out
    float* __restrict__ out_f)                // layer2: NCHW f32 out
{
    __shared__ unsigned short sB[32 * 128];   // 8 KB [ow][ci] swizzled

    int wgid = blockIdx.x;                    // 1024
    int blk  = (wgid & 7) * 128 + (wgid >> 3);
    int owh = blk & 1, oh = (blk >> 1) & 63, b = blk >> 7;
    int ow0 = owh * 32;
    int tid = threadIdx.x, lane = tid & 63, wv = tid >> 6;

    int s_ow = tid >> 3;                      // 0..31
    int ci0  = (tid & 7) * 16;
    int ow_g = ow0 + s_ow;

    const unsigned short* xb = xh + (size_t)b * HH * WW * CH;

    f32x4 acc[2][2];
    #pragma unroll
    for (int a = 0; a < 2; ++a)
        #pragma unroll
        for (int q = 0; q < 2; ++q) acc[a][q] = (f32x4){0.f, 0.f, 0.f, 0.f};

    for (int k = 0; k < 9; ++k) {
        int ky = k / 3, kx = k - ky * 3;

        // ---- per-thread coords ----------------------------------------
        float dy = bf2f(offh[(((size_t)b * OFFC + 2 * k) * HH + oh) * WW + ow_g]);
        float dx = bf2f(offh[(((size_t)b * OFFC + 2 * k + 1) * HH + oh) * WW + ow_g]);
        float ys = (float)(oh - 2 + ky * 2) + dy;
        float xs = (float)(ow_g - 2 + kx * 2) + dx;
        float y0f = floorf(ys), x0f = floorf(xs);
        float fy = ys - y0f, fx = xs - x0f;
        int y0 = (int)y0f, x0 = (int)x0f;
        int y1 = y0 + 1,   x1 = x0 + 1;
        bool vy0 = (y0 >= 0) & (y0 < HH);
        bool vy1 = (y1 >= 0) & (y1 < HH);
        bool vx0 = (x0 >= 0) & (x0 < WW);
        bool vx1 = (x1 >= 0) & (x1 < WW);
        int y0c = min(max(y0, 0), HH - 1), y1c = min(max(y1, 0), HH - 1);
        int x0c = min(max(x0, 0), WW - 1), x1c = min(max(x1, 0), WW - 1);
        float cw0 = (1.f - fy) * (1.f - fx) * ((vy0 && vx0) ? 1.f : 0.f);
        float cw1 = (1.f - fy) * fx         * ((vy0 && vx1) ? 1.f : 0.f);
        float cw2 = fy * (1.f - fx)         * ((vy1 && vx0) ? 1.f : 0.f);
        float cw3 = fy * fx                 * ((vy1 && vx1) ? 1.f : 0.f);

        const unsigned short* p0 = xb + ((size_t)(y0c * WW + x0c)) * CH + ci0;
        const unsigned short* p1 = xb + ((size_t)(y0c * WW + x1c)) * CH + ci0;
        const unsigned short* p2 = xb + ((size_t)(y1c * WW + x0c)) * CH + ci0;
        const unsigned short* p3 = xb + ((size_t)(y1c * WW + x1c)) * CH + ci0;

        // ---- cooperative 16B loads + f32 blend -------------------------
        bf16x8 v00 = *(const bf16x8*)(p0),     v01 = *(const bf16x8*)(p0 + 8);
        bf16x8 v10 = *(const bf16x8*)(p1),     v11 = *(const bf16x8*)(p1 + 8);
        bf16x8 v20 = *(const bf16x8*)(p2),     v21 = *(const bf16x8*)(p2 + 8);
        bf16x8 v30 = *(const bf16x8*)(p3),     v31 = *(const bf16x8*)(p3 + 8);

        union { bf16x8 v8; unsigned short u[8]; } w0, w1;
        #pragma unroll
        for (int j = 0; j < 8; ++j) {
            float a0 = cw0 * bf2f((unsigned short)v00[j])
                     + cw1 * bf2f((unsigned short)v10[j])
                     + cw2 * bf2f((unsigned short)v20[j])
                     + cw3 * bf2f((unsigned short)v30[j]);
            float a1 = cw0 * bf2f((unsigned short)v01[j])
                     + cw1 * bf2f((unsigned short)v11[j])
                     + cw2 * bf2f((unsigned short)v21[j])
                     + cw3 * bf2f((unsigned short)v31[j]);
            w0.u[j] = f2bf(a0);
            w1.u[j] = f2bf(a1);
        }
        int base = s_ow * 256 + ci0 * 2;
        int swz  = (s_ow & 7) << 4;
        *(bf16x8*)((char*)sB + ( base       ^ swz)) = w0.v8;
        *(bf16x8*)((char*)sB + ((base + 16) ^ swz)) = w1.v8;
        __syncthreads();

        // ---- MFMA: 4 K-chunks of 32 ci --------------------------------
        const unsigned short* wk = wpk + (size_t)k * 16384;
        #pragma unroll
        for (int kk = 0; kk < 4; ++kk) {
            bf16x8 a0 = *(const bf16x8*)(wk + (kk * 8 + 2 * wv)     * 512 + lane * 8);
            bf16x8 a1 = *(const bf16x8*)(wk + (kk * 8 + 2 * wv + 1) * 512 + lane * 8);
            #pragma unroll
            for (int owt = 0; owt < 2; ++owt) {
                int owl = owt * 16 + (lane & 15);
                int rbyte = (owl * 256 + (kk * 32 + (lane >> 4) * 8) * 2)
                            ^ ((owl & 7) << 4);
                bf16x8 bf = *(const bf16x8*)((const char*)sB + rbyte);
                acc[0][owt] = __builtin_amdgcn_mfma_f32_16x16x32_bf16(
                                  a0, bf, acc[0][owt], 0, 0, 0);
                acc[1][owt] = __builtin_amdgcn_mfma_f32_16x16x32_bf16(
                                  a1, bf, acc[1][owt], 0, 0, 0);
            }
        }
        __syncthreads();
    }

    // ---- epilogue ------------------------------------------------------
    if (out_h != nullptr) {
        // layer 1: BN + ReLU -> NHWC bf16
        #pragma unroll
        for (int otl = 0; otl < 2; ++otl) {
            int ob = (2 * wv + otl) * 16 + (lane >> 4) * 4;
            float inv[4], sh[4];
            #pragma unroll
            for (int r = 0; r < 4; ++r) {
                int o = ob + r;
                float iv = g[o] / sqrtf(v[o] + 1e-5f);
                inv[r] = iv; sh[r] = beta[o] - m[o] * iv;
            }
            #pragma unroll
            for (int owt = 0; owt < 2; ++owt) {
                int ow = ow0 + owt * 16 + (lane & 15);
                union { bf16x4 v4; unsigned short u[4]; } pk;
                #pragma unroll
                for (int r = 0; r < 4; ++r) {
                    float val = acc[otl][owt][r] * inv[r] + sh[r];
                    pk.u[r] = f2bf(fmaxf(val, 0.f));
                }
                *(bf16x4*)(out_h + ((size_t)(b * HH + oh) * WW + ow) * CH + ob) = pk.v4;
            }
        }
    } else {
        // layer 2: BN + residual + ReLU -> NCHW f32
        #pragma unroll
        for (int otl = 0; otl < 2; ++otl) {
            #pragma unroll
            for (int r = 0; r < 4; ++r) {
                int o = (2 * wv + otl) * 16 + (lane >> 4) * 4 + r;
                float iv = g[o] / sqrtf(v[o] + 1e-5f);
                float sh = beta[o] - m[o] * iv;
                #pragma unroll
                for (int owt = 0; owt < 2; ++owt) {
                    int ow = ow0 + owt * 16 + (lane & 15);
                    size_t idx = (((size_t)b * CH + o) * HH + oh) * WW + ow;
                    float val = acc[otl][owt][r] * iv + sh + residual[idx];
                    out_f[idx] = fmaxf(val, 0.f);
                }
            }
        }
    }
}

// ---------------------------------------------------------------------------
extern "C" void kernel_launch(void* const* d_in, const int* in_sizes, int n_in,
                              void* d_out, int out_size, void* d_ws, size_t ws_size,
                              hipStream_t stream)
{
    const float* x      = (const float*)d_in[0];
    const float* w_off1 = (const float*)d_in[1];
    const float* b_off1 = (const float*)d_in[2];
    const float* w_dc1  = (const float*)d_in[3];
    const float* g1     = (const float*)d_in[4];
    const float* beta1  = (const float*)d_in[5];
    const float* m1     = (const float*)d_in[6];
    const float* v1     = (const float*)d_in[7];
    const float* w_off2 = (const float*)d_in[8];
    const float* b_off2 = (const float*)d_in[9];
    const float* w_dc2  = (const float*)d_in[10];
    const float* g2     = (const float*)d_in[11];
    const float* beta2  = (const float*)d_in[12];
    const float* m2     = (const float*)d_in[13];
    const float* v2     = (const float*)d_in[14];
    float* out = (float*)d_out;

    char* ws = (char*)d_ws;
    unsigned short* xh    = (unsigned short*)ws;                  // 8,388,608 B
    unsigned short* out1h = (unsigned short*)(ws + 8388608);      // 8,388,608 B
    unsigned short* offh  = (unsigned short*)(ws + 16777216);     // 1,179,648 B
    unsigned short* wpk1  = (unsigned short*)(ws + 17956864);     //   294,912 B
    unsigned short* wpk2  = (unsigned short*)(ws + 18251776);     //   294,912 B
    unsigned short* wpo1  = (unsigned short*)(ws + 18546688);     //    73,728 B
    unsigned short* wpo2  = (unsigned short*)(ws + 18620416);     //    73,728 B
    // total 18,694,144 B

    pack_all_kernel<<<1440, 256, 0, stream>>>(w_dc1, w_dc2, w_off1, w_off2,
                                              wpk1, wpk2, wpo1, wpo2);
    to_nhwc_kernel<<<512, 256, 0, stream>>>(x, xh);

    // Layer 1
    off_conv_mfma_kernel<<<512, 256, 0, stream>>>(xh, wpo1, b_off1, offh);
    deform_mfma2_kernel<<<1024, 256, 0, stream>>>(xh, offh, wpk1,
                                                  g1, beta1, m1, v1,
                                                  nullptr, out1h, nullptr);
    // Layer 2
    off_conv_mfma_kernel<<<512, 256, 0, stream>>>(out1h, wpo2, b_off2, offh);
    deform_mfma2_kernel<<<1024, 256, 0, stream>>>(out1h, offh, wpk2,
                                                  g2, beta2, m2, v2,
                                                  x, nullptr, out);
}